// Round 10
// baseline (1472.155 us; speedup 1.0000x reference)
//
#include <hip/hip_runtime.h>
#include <math.h>

#define B_ 32
#define S_ 511
#define T_ 512
#define D_ 512
#define H_ 8
#define HD_ 64
#define L_ 4
#define P_ 501
#define PD_ 32
#define FD_ 448
#define DFF_ 2048

typedef __attribute__((ext_vector_type(8))) short bf16x8;
typedef __attribute__((ext_vector_type(4))) float f32x4;

#define GLDS16(gp, lp) __builtin_amdgcn_global_load_lds(                      \
    (const __attribute__((address_space(1))) void*)(gp),                      \
    (__attribute__((address_space(3))) void*)(lp), 16, 0, 0)

__device__ __forceinline__ unsigned short f2bf(float f) {
  union { float f; unsigned int u; } c; c.f = f;
  unsigned int r = c.u + 0x7FFFu + ((c.u >> 16) & 1u);  // RNE
  return (unsigned short)(r >> 16);
}

// ---- weight transpose+convert: fp32 [K][N] -> bf16 rows [nofs..nofs+N) of [..][K] ----
__global__ __launch_bounds__(256) void wtrans_kernel(
    const float* __restrict__ in, unsigned short* __restrict__ out, int K, int N,
    size_t lstride, int nofs)
{
  __shared__ float t[64][65];
  const int l = blockIdx.z;
  in  += (size_t)l * K * N;
  out += (size_t)l * lstride + (size_t)nofs * K;
  const int k0 = blockIdx.x * 64, n0 = blockIdx.y * 64;
  const int tx = threadIdx.x & 63, ty = threadIdx.x >> 6;
#pragma unroll
  for (int i = 0; i < 16; ++i) {
    int r = ty + i * 4;
    t[r][tx] = in[(size_t)(k0 + r) * N + n0 + tx];
  }
  __syncthreads();
#pragma unroll
  for (int i = 0; i < 16; ++i) {
    int r = ty + i * 4;
    out[(size_t)(n0 + r) * K + k0 + tx] = f2bf(t[tx][r]);
  }
}

// ---------------- embedding + positional encoding (dual write fp32 + bf16) ----------------
__global__ __launch_bounds__(256) void embed_kernel(
    const float* __restrict__ runs, const float* __restrict__ wickets,
    const float* __restrict__ overs, const int* __restrict__ batters,
    const int* __restrict__ bowlers, const float* __restrict__ pemb,
    const float* __restrict__ Wf, const float* __restrict__ bfv,
    const float* __restrict__ qtok, float* __restrict__ x,
    unsigned short* __restrict__ xb)
{
  size_t idx = (size_t)blockIdx.x * 256 + threadIdx.x;
  const size_t total = (size_t)B_ * T_ * D_;
  if (idx >= total) return;
  int d = (int)(idx % D_);
  int t = (int)((idx / D_) % T_);
  int b = (int)(idx / ((size_t)D_ * T_));
  float val;
  if (t < S_) {
    size_t st = (size_t)b * S_ + t;
    if (d < FD_) {
      val = runs[st] * Wf[d] + wickets[st] * Wf[FD_ + d] + overs[st] * Wf[2 * FD_ + d] + bfv[d];
    } else if (d < FD_ + PD_) {
      val = pemb[(size_t)batters[st] * PD_ + (d - FD_)];
    } else {
      val = pemb[(size_t)bowlers[st] * PD_ + (d - FD_ - PD_)];
    }
  } else {
    val = qtok[d];
  }
  float div = expf((float)(2 * (d >> 1)) * (-9.210340371976184f / (float)D_));
  float ang = (float)t * div;
  val += (d & 1) ? cosf(ang) : sinf(ang);
  x[idx] = val;
  xb[idx] = f2bf(val);
}

// ======== 256x256 / 8-wave / BK=64 GEMM with counted-vmcnt prefetch ========
// ACT==0: fp32 C ; ACT==1: GELU->bf16 Cb ; ACT==4: bf16 Cb, split bias (QK fused)
template<int ACT>
__global__ __launch_bounds__(512) void mfma_gemm256(
    const unsigned short* __restrict__ A, const unsigned short* __restrict__ Bt,
    const float* __restrict__ bias, float* __restrict__ C,
    unsigned short* __restrict__ Cb, int N, int K, const float* __restrict__ bias2)
{
  __shared__ unsigned short As[2][256 * 64];
  __shared__ unsigned short Bs[2][256 * 64];
  const int tid = threadIdx.x;
  const int m0 = blockIdx.y * 256, n0 = blockIdx.x * 256;
  const int lane = tid & 63, w = tid >> 6;
  const int wr = w >> 2, wc = w & 3;           // 2M x 4N waves; wave tile 128x64
  const int lr = lane & 15, lg = lane >> 4;

  f32x4 acc[8][4] = {};

  const unsigned short* gA = A + (size_t)m0 * K;
  const unsigned short* gB = Bt + (size_t)n0 * K;

#define STAGE256(buf, kt)                                                     \
  do {                                                                        \
    const int k0s = (kt) * 64;                                                \
    _Pragma("unroll")                                                         \
    for (int i = 0; i < 4; ++i) {                                             \
      int s = i * 512 + tid;                                                  \
      GLDS16(gA + (size_t)(s >> 3) * K + k0s + (s & 7) * 8, &As[buf][s * 8]); \
    }                                                                         \
    _Pragma("unroll")                                                         \
    for (int i = 0; i < 4; ++i) {                                             \
      int s = i * 512 + tid;                                                  \
      GLDS16(gB + (size_t)(s >> 3) * K + k0s + (s & 7) * 8, &Bs[buf][s * 8]); \
    }                                                                         \
  } while (0)

  const int NK = K / 64;
  STAGE256(0, 0);
  for (int kt = 0; kt < NK; ++kt) {
    // 1) issue next K-tile into the other buffer (its previous readers finished
    //    at the end-of-iteration barrier of kt-1)
    if (kt + 1 < NK) {
      STAGE256((kt + 1) & 1, kt + 1);
      // 2) own-wave kt loads done; the 8 just-issued stay in flight (T4)
      asm volatile("s_waitcnt vmcnt(8)" ::: "memory");
    } else {
      asm volatile("s_waitcnt vmcnt(0)" ::: "memory");
    }
    // 3) all waves' kt data resident
    __builtin_amdgcn_s_barrier();
    __builtin_amdgcn_sched_barrier(0);
    // 4) compute K-tile kt
    {
      const unsigned short* Ab = &As[kt & 1][0];
      const unsigned short* Bb = &Bs[kt & 1][0];
      bf16x8 bfrag[4][2];
#pragma unroll
      for (int ni = 0; ni < 4; ++ni) {
        bfrag[ni][0] = *(const bf16x8*)&Bb[(wc * 64 + ni * 16 + lr) * 64 + lg * 8];
        bfrag[ni][1] = *(const bf16x8*)&Bb[(wc * 64 + ni * 16 + lr) * 64 + 32 + lg * 8];
      }
#pragma unroll
      for (int mi = 0; mi < 8; ++mi) {
        bf16x8 a0 = *(const bf16x8*)&Ab[(wr * 128 + mi * 16 + lr) * 64 + lg * 8];
        bf16x8 a1 = *(const bf16x8*)&Ab[(wr * 128 + mi * 16 + lr) * 64 + 32 + lg * 8];
#pragma unroll
        for (int ni = 0; ni < 4; ++ni) {
          acc[mi][ni] = __builtin_amdgcn_mfma_f32_16x16x32_bf16(a0, bfrag[ni][0], acc[mi][ni], 0, 0, 0);
          acc[mi][ni] = __builtin_amdgcn_mfma_f32_16x16x32_bf16(a1, bfrag[ni][1], acc[mi][ni], 0, 0, 0);
        }
      }
    }
    // 5) all waves done reading buf[kt&1] before iteration kt+1 overwrites it
    __builtin_amdgcn_s_barrier();
    __builtin_amdgcn_sched_barrier(0);
  }
#undef STAGE256

  // epilogue: row = m0 + wr*128 + mi*16 + lg*4 + r ; col = n0 + wc*64 + ni*16 + lr
  const int crow0 = m0 + wr * 128 + lg * 4;
  const int ccol0 = n0 + wc * 64 + lr;
#pragma unroll
  for (int mi = 0; mi < 8; ++mi) {
#pragma unroll
    for (int ni = 0; ni < 4; ++ni) {
      const int col = ccol0 + ni * 16;
      const float bcol = (ACT == 4) ? ((col < 512) ? bias[col] : bias2[col - 512])
                                    : bias[col];
#pragma unroll
      for (int r = 0; r < 4; ++r) {
        const int row = crow0 + mi * 16 + r;
        float v = acc[mi][ni][r] + bcol;
        if (ACT == 1) {
          v = 0.5f * v * (1.0f + erff(v * 0.70710678118654752f));
          Cb[(size_t)row * N + col] = f2bf(v);
        } else if (ACT == 4) {
          Cb[(size_t)row * N + col] = f2bf(v);
        } else {
          C[(size_t)row * N + col] = v;
        }
      }
    }
  }
}

// ---------------- legacy 128x128 GEMM (kept for V projection: ACT==3 -> vt) ----------------
template<int ACT>
__global__ __launch_bounds__(256) void mfma_gemm(
    const unsigned short* __restrict__ A, const unsigned short* __restrict__ Bt,
    const float* __restrict__ bias, float* __restrict__ C,
    unsigned short* __restrict__ Cb, int N, int K, const float* __restrict__ bias2)
{
  __shared__ unsigned short As[2][128 * 32];
  __shared__ unsigned short Bs[2][128 * 32];
  __shared__ unsigned short Ts[ACT == 3 ? 128 * 136 : 1];
  const int tid = threadIdx.x;
  const int m0 = blockIdx.y * 128, n0 = blockIdx.x * 128;
  const int lane = tid & 63, w = tid >> 6;
  const int wr = w >> 1, wc = w & 1;
  const int lr = lane & 15, lg = lane >> 4;

  f32x4 acc[4][4] = {};

  const int srow = w * 16 + (lane >> 2);
  const int sc8 = (lane & 3) * 8;
  const unsigned short* gA0 = A + (size_t)(m0 + srow) * K + sc8;
  const unsigned short* gA1 = gA0 + (size_t)64 * K;
  const unsigned short* gB0 = Bt + (size_t)(n0 + srow) * K + sc8;
  const unsigned short* gB1 = gB0 + (size_t)64 * K;
  const int lofs0 = (w * 16) * 32;
  const int lofs1 = (64 + w * 16) * 32;

#define STAGE(buf, kk)                                                        \
  do {                                                                        \
    GLDS16(gA0 + (kk), &As[buf][lofs0]);                                      \
    GLDS16(gA1 + (kk), &As[buf][lofs1]);                                      \
    GLDS16(gB0 + (kk), &Bs[buf][lofs0]);                                      \
    GLDS16(gB1 + (kk), &Bs[buf][lofs1]);                                      \
  } while (0)

  STAGE(0, 0);
  __syncthreads();
  int cur = 0;
  for (int k0 = 0; k0 < K; k0 += 32) {
    if (k0 + 32 < K) STAGE(cur ^ 1, k0 + 32);
    bf16x8 af[4], bfr[4];
#pragma unroll
    for (int f = 0; f < 4; ++f) {
      af[f]  = *(const bf16x8*)&As[cur][(wr * 64 + f * 16 + lr) * 32 + lg * 8];
      bfr[f] = *(const bf16x8*)&Bs[cur][(wc * 64 + f * 16 + lr) * 32 + lg * 8];
    }
#pragma unroll
    for (int i = 0; i < 4; ++i)
#pragma unroll
      for (int j = 0; j < 4; ++j)
        acc[i][j] = __builtin_amdgcn_mfma_f32_16x16x32_bf16(af[i], bfr[j], acc[i][j], 0, 0, 0);
    __syncthreads();
    cur ^= 1;
  }
#undef STAGE

  const int crow0 = m0 + wr * 64 + lg * 4;
  const int ccol0 = n0 + wc * 64 + lr;
#pragma unroll
  for (int i = 0; i < 4; ++i) {
#pragma unroll
    for (int j = 0; j < 4; ++j) {
      const int col = ccol0 + j * 16;
      const float bcol = bias[col];
#pragma unroll
      for (int r = 0; r < 4; ++r) {
        const int row = crow0 + i * 16 + r;
        float v = acc[i][j][r] + bcol;
        if (ACT == 3) {
          Ts[(wc * 64 + j * 16 + lr) * 136 + (wr * 64 + i * 16 + lg * 4 + r)] = f2bf(v);
        } else {
          C[(size_t)row * N + col] = v;
        }
      }
    }
  }
  if (ACT == 3) {
    __syncthreads();
    const int c = tid & 127, h2 = tid >> 7;
    const int hh = (n0 + c) >> 6, hd = (n0 + c) & 63;
    const int bb = m0 >> 9, t0 = (m0 & (T_ - 1)) + h2 * 64;
    unsigned short* dst = Cb + (((size_t)bb * H_ + hh) * HD_ + hd) * T_ + t0;
#pragma unroll
    for (int e = 0; e < 8; ++e)
      *(bf16x8*)(dst + e * 8) = *(const bf16x8*)&Ts[c * 136 + h2 * 64 + e * 8];
  }
}

// ---------------- MFMA flash attention: paired tiles + K/V double-buffer ----------------
__global__ __launch_bounds__(256) void flash_mfma_kernel(
    const unsigned short* __restrict__ qk, const unsigned short* __restrict__ vt,
    unsigned short* __restrict__ o,
    const int* __restrict__ batters, const int* __restrict__ bowlers,
    const float* __restrict__ rec_sp, const float* __restrict__ bow_sp,
    const float* __restrict__ bat_sp, int l)
{
  __shared__ unsigned short QPs[64 * 70];
  __shared__ unsigned short Ks[2][64 * 70];
  __shared__ unsigned short Vs[2][64 * 70];
  __shared__ int aq_s[64], ak_s[2][64];

  const int p = blockIdx.x, h = blockIdx.y, b = blockIdx.z;
  const int tid = threadIdx.x;
  const int w = tid >> 6, lane = tid & 63;
  const int c = lane & 15, g = lane >> 4;
  const int NT = T_ / 64;

  int mode = 0; float hs = 0.f;
  if (h == 0) { mode = 1; hs = rec_sp[l]; }
  else if (h == 1) { mode = 2; hs = bow_sp[l]; }
  else if (h == 2) { mode = 3; hs = bat_sp[l]; }
  const int* actors = (mode == 2) ? bowlers : batters;

  const int sr = tid >> 2, sch = (tid & 3) * 16;
  const unsigned short* qbase = qk + (size_t)b * T_ * 1024 + h * HD_;
  const unsigned short* kbase = qbase + 512;
  const unsigned short* vbase = vt + ((size_t)(b * H_ + h) * HD_ + sr) * T_;

  for (int ph = 0; ph < 2; ++ph) {
    const int qt = (ph == 0) ? p : (NT - 1 - p);
    const int q0 = qt * 64;
    __syncthreads();

    {
      const unsigned short* src = qbase + (size_t)(q0 + sr) * 1024 + sch;
      *(bf16x8*)&QPs[sr * 70 + sch]     = *(const bf16x8*)src;
      *(bf16x8*)&QPs[sr * 70 + sch + 8] = *(const bf16x8*)(src + 8);
      const unsigned short* ksrc = kbase + (size_t)sr * 1024 + sch;
      *(bf16x8*)&Ks[0][sr * 70 + sch]     = *(const bf16x8*)ksrc;
      *(bf16x8*)&Ks[0][sr * 70 + sch + 8] = *(const bf16x8*)(ksrc + 8);
      const unsigned short* vsrc = vbase + sch;
      *(bf16x8*)&Vs[0][sr * 70 + sch]     = *(const bf16x8*)vsrc;
      *(bf16x8*)&Vs[0][sr * 70 + sch + 8] = *(const bf16x8*)(vsrc + 8);
    }
    if (tid < 64) {
      int qg_ = q0 + tid;
      aq_s[tid] = (mode >= 2 && qg_ < S_) ? actors[(size_t)b * S_ + qg_] : -1;
      ak_s[0][tid] = (mode >= 2 && tid < S_) ? actors[(size_t)b * S_ + tid] : -1;
    }
    __syncthreads();

    bf16x8 af0 = *(const bf16x8*)&QPs[(w * 16 + c) * 70 + g * 8];
    bf16x8 af1 = *(const bf16x8*)&QPs[(w * 16 + c) * 70 + 32 + g * 8];
    int aq4[4];
#pragma unroll
    for (int r = 0; r < 4; ++r) aq4[r] = aq_s[w * 16 + 4 * g + r];

    float m_r[4] = {-INFINITY, -INFINITY, -INFINITY, -INFINITY};
    float l_r[4] = {0.f, 0.f, 0.f, 0.f};
    f32x4 o_acc[4] = {};
    int cur = 0;

    for (int kt = 0; kt <= qt; ++kt) {
      const int k0 = kt * 64;
      const bool has_next = kt < qt;
      bf16x8 kr0, kr1, vr0, vr1;
      int akn = -1;
      if (has_next) {
        const int k0n = k0 + 64;
        const unsigned short* ksrc = kbase + (size_t)(k0n + sr) * 1024 + sch;
        kr0 = *(const bf16x8*)ksrc;
        kr1 = *(const bf16x8*)(ksrc + 8);
        const unsigned short* vsrc = vbase + k0n + sch;
        vr0 = *(const bf16x8*)vsrc;
        vr1 = *(const bf16x8*)(vsrc + 8);
        if (tid < 64) {
          int kg_ = k0n + tid;
          akn = (mode >= 2 && kg_ < S_) ? actors[(size_t)b * S_ + kg_] : -1;
        }
      }

      if (q0 + w * 16 + 15 >= k0) {
        f32x4 s[4] = {};
#pragma unroll
        for (int f = 0; f < 4; ++f) {
          bf16x8 b0 = *(const bf16x8*)&Ks[cur][(f * 16 + c) * 70 + g * 8];
          bf16x8 b1 = *(const bf16x8*)&Ks[cur][(f * 16 + c) * 70 + 32 + g * 8];
          s[f] = __builtin_amdgcn_mfma_f32_16x16x32_bf16(af0, b0, s[f], 0, 0, 0);
          s[f] = __builtin_amdgcn_mfma_f32_16x16x32_bf16(af1, b1, s[f], 0, 0, 0);
        }
        int ak4[4];
#pragma unroll
        for (int f = 0; f < 4; ++f) ak4[f] = ak_s[cur][f * 16 + c];

        float sv[4][4];
#pragma unroll
        for (int f = 0; f < 4; ++f) {
          const int kg = k0 + f * 16 + c;
#pragma unroll
          for (int r = 0; r < 4; ++r) {
            const int qg = q0 + w * 16 + 4 * g + r;
            float val = s[f][r] * 0.125f;
            if (mode == 1) {
              val = fmaf(hs, (float)kg * (1.0f / (float)T_), val);
            } else if (mode >= 2) {
              float eq = (qg == S_ || kg == S_) ? 1.0f : ((aq4[r] == ak4[f]) ? 1.0f : 0.0f);
              val = fmaf(hs, eq, val);
            }
            if (kg > qg) val = -INFINITY;
            sv[f][r] = val;
          }
        }
        float cr[4];
#pragma unroll
        for (int r = 0; r < 4; ++r) {
          float pm = fmaxf(fmaxf(sv[0][r], sv[1][r]), fmaxf(sv[2][r], sv[3][r]));
          pm = fmaxf(pm, __shfl_xor(pm, 1));
          pm = fmaxf(pm, __shfl_xor(pm, 2));
          pm = fmaxf(pm, __shfl_xor(pm, 4));
          pm = fmaxf(pm, __shfl_xor(pm, 8));
          float m_new = fmaxf(m_r[r], pm);
          cr[r] = __expf(m_r[r] - m_new);
          m_r[r] = m_new;
        }
        float rs[4] = {0.f, 0.f, 0.f, 0.f};
#pragma unroll
        for (int f = 0; f < 4; ++f) {
#pragma unroll
          for (int r = 0; r < 4; ++r) {
            float pv = __expf(sv[f][r] - m_r[r]);
            rs[r] += pv;
            QPs[(w * 16 + 4 * g + r) * 70 + f * 16 + c] = f2bf(pv);
          }
        }
#pragma unroll
        for (int r = 0; r < 4; ++r) {
          float t = rs[r];
          t += __shfl_xor(t, 1);
          t += __shfl_xor(t, 2);
          t += __shfl_xor(t, 4);
          t += __shfl_xor(t, 8);
          l_r[r] = l_r[r] * cr[r] + t;
#pragma unroll
          for (int f = 0; f < 4; ++f) o_acc[f][r] *= cr[r];
        }
        bf16x8 pa0 = *(const bf16x8*)&QPs[(w * 16 + c) * 70 + g * 8];
        bf16x8 pa1 = *(const bf16x8*)&QPs[(w * 16 + c) * 70 + 32 + g * 8];
#pragma unroll
        for (int f = 0; f < 4; ++f) {
          bf16x8 v0 = *(const bf16x8*)&Vs[cur][(f * 16 + c) * 70 + g * 8];
          bf16x8 v1 = *(const bf16x8*)&Vs[cur][(f * 16 + c) * 70 + 32 + g * 8];
          o_acc[f] = __builtin_amdgcn_mfma_f32_16x16x32_bf16(pa0, v0, o_acc[f], 0, 0, 0);
          o_acc[f] = __builtin_amdgcn_mfma_f32_16x16x32_bf16(pa1, v1, o_acc[f], 0, 0, 0);
        }
      }

      if (has_next) {
        *(bf16x8*)&Ks[cur ^ 1][sr * 70 + sch]     = kr0;
        *(bf16x8*)&Ks[cur ^ 1][sr * 70 + sch + 8] = kr1;
        *(bf16x8*)&Vs[cur ^ 1][sr * 70 + sch]     = vr0;
        *(bf16x8*)&Vs[cur ^ 1][sr * 70 + sch + 8] = vr1;
        if (tid < 64) ak_s[cur ^ 1][tid] = akn;
        __syncthreads();
        cur ^= 1;
      }
    }

#pragma unroll
    for (int r = 0; r < 4; ++r) {
      const float inv = 1.0f / l_r[r];
      const int row = q0 + w * 16 + 4 * g + r;
#pragma unroll
      for (int f = 0; f < 4; ++f)
        o[((size_t)b * T_ + row) * D_ + h * HD_ + f * 16 + c] = f2bf(o_acc[f][r] * inv);
    }
  }
}

// ---------------- residual add + LayerNorm (dual write fp32 + bf16) ----------------
__global__ __launch_bounds__(256) void add_ln_kernel(
    float* __restrict__ x, const float* __restrict__ y,
    const float* __restrict__ g, const float* __restrict__ be,
    unsigned short* __restrict__ xb)
{
  int row = blockIdx.x;
  int tid = threadIdx.x;
  size_t base = (size_t)row * D_;
  float v0 = x[base + tid] + y[base + tid];
  float v1 = x[base + tid + 256] + y[base + tid + 256];
  float s = v0 + v1;
  float s2 = v0 * v0 + v1 * v1;
  __shared__ float redA[4], redB[4];
#pragma unroll
  for (int off = 32; off > 0; off >>= 1) {
    s  += __shfl_down(s, off);
    s2 += __shfl_down(s2, off);
  }
  if ((tid & 63) == 0) { redA[tid >> 6] = s; redB[tid >> 6] = s2; }
  __syncthreads();
  float st  = redA[0] + redA[1] + redA[2] + redA[3];
  float s2t = redB[0] + redB[1] + redB[2] + redB[3];
  float mu = st * (1.0f / (float)D_);
  float var = s2t * (1.0f / (float)D_) - mu * mu;
  float r = rsqrtf(var + 1e-5f);
  float o0 = (v0 - mu) * r * g[tid] + be[tid];
  float o1 = (v1 - mu) * r * g[tid + 256] + be[tid + 256];
  x[base + tid]        = o0;
  x[base + tid + 256]  = o1;
  xb[base + tid]       = f2bf(o0);
  xb[base + tid + 256] = f2bf(o1);
}

// ---------------- final: out[b,:] = x[b,T-1,:] @ Wout + bout ----------------
__global__ __launch_bounds__(256) void final_kernel(
    const float* __restrict__ x, const float* __restrict__ Wout,
    const float* __restrict__ bout, float* __restrict__ out)
{
  __shared__ float xs[D_];
  int b = blockIdx.x;
  int n = blockIdx.y * 256 + threadIdx.x;
  const float* xr = x + ((size_t)b * T_ + (T_ - 1)) * D_;
  xs[threadIdx.x] = xr[threadIdx.x];
  xs[threadIdx.x + 256] = xr[threadIdx.x + 256];
  __syncthreads();
  float acc = bout[n];
  for (int kk = 0; kk < D_; ++kk)
    acc = fmaf(xs[kk], Wout[(size_t)kk * D_ + n], acc);
  out[(size_t)b * D_ + n] = acc;
}

extern "C" void kernel_launch(void* const* d_in, const int* in_sizes, int n_in,
                              void* d_out, int out_size, void* d_ws, size_t ws_size,
                              hipStream_t stream)
{
  const float* runs    = (const float*)d_in[0];
  const float* wickets = (const float*)d_in[1];
  const float* overs   = (const float*)d_in[2];
  const int*   batters = (const int*)d_in[3];
  const int*   bowlers = (const int*)d_in[4];
  const float* pemb    = (const float*)d_in[5];
  const float* Wf      = (const float*)d_in[6];
  const float* bfv     = (const float*)d_in[7];
  const float* qtok    = (const float*)d_in[8];
  const float* Wq      = (const float*)d_in[9];
  const float* bq      = (const float*)d_in[10];
  const float* Wk      = (const float*)d_in[11];
  const float* bk      = (const float*)d_in[12];
  const float* Wv      = (const float*)d_in[13];
  const float* bv      = (const float*)d_in[14];
  const float* Wo      = (const float*)d_in[15];
  const float* bo      = (const float*)d_in[16];
  const float* rec_s   = (const float*)d_in[17];
  const float* bow_s   = (const float*)d_in[18];
  const float* bat_s   = (const float*)d_in[19];
  const float* W1      = (const float*)d_in[20];
  const float* b1      = (const float*)d_in[21];
  const float* W2      = (const float*)d_in[22];
  const float* b2      = (const float*)d_in[23];
  const float* g1      = (const float*)d_in[24];
  const float* be1     = (const float*)d_in[25];
  const float* g2      = (const float*)d_in[26];
  const float* be2     = (const float*)d_in[27];
  const float* Wout    = (const float*)d_in[28];
  const float* bout    = (const float*)d_in[29];

  float* ws = (float*)d_ws;
  const size_t n1 = (size_t)B_ * T_ * D_;  // 8M elements
  float* x  = ws;
  float* yb = ws + n1;
  unsigned short* xb = (unsigned short*)(ws + 2 * n1);
  unsigned short* qkb = xb + n1;     // fused QK output [M][1024]
  unsigned short* vt  = qkb + 2 * n1;
  unsigned short* ob  = vt + n1;
  unsigned short* wt  = ob + n1;
  unsigned short* hb  = qkb;  // FFN hidden aliases qkb+vt+ob

  const size_t qk_lstride = (size_t)1024 * 512;
  unsigned short* wqk = wt;
  unsigned short* wtv = wqk + (size_t)L_ * qk_lstride;
  unsigned short* wto = wtv + (size_t)L_ * D_ * D_;
  unsigned short* wt1 = wto + (size_t)L_ * D_ * D_;
  unsigned short* wt2 = wt1 + (size_t)L_ * D_ * DFF_;

  const int M = B_ * T_;
  dim3 blk(256);
  dim3 blk512(512);

  wtrans_kernel<<<dim3(8, 8, L_),  blk, 0, stream>>>(Wq, wqk, D_, D_, qk_lstride, 0);
  wtrans_kernel<<<dim3(8, 8, L_),  blk, 0, stream>>>(Wk, wqk, D_, D_, qk_lstride, 512);
  wtrans_kernel<<<dim3(8, 8, L_),  blk, 0, stream>>>(Wv, wtv, D_, D_, (size_t)D_ * D_, 0);
  wtrans_kernel<<<dim3(8, 8, L_),  blk, 0, stream>>>(Wo, wto, D_, D_, (size_t)D_ * D_, 0);
  wtrans_kernel<<<dim3(8, 32, L_), blk, 0, stream>>>(W1, wt1, D_, DFF_, (size_t)D_ * DFF_, 0);
  wtrans_kernel<<<dim3(32, 8, L_), blk, 0, stream>>>(W2, wt2, DFF_, D_, (size_t)DFF_ * D_, 0);

  {
    size_t total = (size_t)B_ * T_ * D_;
    int nb = (int)((total + 255) / 256);
    embed_kernel<<<nb, blk, 0, stream>>>(runs, wickets, overs, batters, bowlers,
                                         pemb, Wf, bfv, qtok, x, xb);
  }

  for (int l = 0; l < L_; ++l) {
    // fused Q+K projection -> qkb [M][1024]
    mfma_gemm256<4><<<dim3(1024 / 256, M / 256), blk512, 0, stream>>>(
        xb, wqk + (size_t)l * qk_lstride, bq + l * D_, nullptr, qkb, 1024, D_,
        bk + l * D_);
    // V projection -> vt [B,H,64,T] (legacy kernel, transpose epilogue)
    mfma_gemm<3><<<dim3(D_ / 128, M / 128), blk, 0, stream>>>(
        xb, wtv + (size_t)l * D_ * D_, bv + l * D_, nullptr, vt, D_, D_, nullptr);

    flash_mfma_kernel<<<dim3(T_ / 128, H_, B_), blk, 0, stream>>>(
        qkb, vt, ob, batters, bowlers, rec_s, bow_s, bat_s, l);

    mfma_gemm256<0><<<dim3(D_ / 256, M / 256), blk512, 0, stream>>>(
        ob, wto + (size_t)l * D_ * D_, bo + l * D_, yb, nullptr, D_, D_, nullptr);
    add_ln_kernel<<<M, blk, 0, stream>>>(x, yb, g1 + l * D_, be1 + l * D_, xb);

    mfma_gemm256<1><<<dim3(DFF_ / 256, M / 256), blk512, 0, stream>>>(
        xb, wt1 + (size_t)l * D_ * DFF_, b1 + l * DFF_, nullptr, hb, DFF_, D_, nullptr);
    mfma_gemm256<0><<<dim3(D_ / 256, M / 256), blk512, 0, stream>>>(
        hb, wt2 + (size_t)l * DFF_ * D_, b2 + l * D_, yb, nullptr, D_, DFF_, nullptr);
    add_ln_kernel<<<M, blk, 0, stream>>>(x, yb, g2 + l * D_, be2 + l * D_, xb);
  }

  final_kernel<<<dim3(B_, D_ / 256), blk, 0, stream>>>(x, Wout, bout, (float*)d_out);
}